// Round 1
// baseline (20712.576 us; speedup 1.0000x reference)
//
#include <hip/hip_runtime.h>
#include <math.h>

#define BB 2
#define SS 1024
#define HH 16
#define DD 1024
#define DHH 64
#define FFDIM 4096
#define VV 32000
#define LL 8
#define MM (BB * SS)

// ---------------- block reduce helpers (blockDim.x == 256 → 4 waves) --------
__device__ __forceinline__ float block_reduce_sum(float val, float* red) {
    int lane = threadIdx.x & 63, wv = threadIdx.x >> 6;
#pragma unroll
    for (int off = 32; off; off >>= 1) val += __shfl_down(val, off, 64);
    if (lane == 0) red[wv] = val;
    __syncthreads();
    float t = red[0] + red[1] + red[2] + red[3];
    __syncthreads();
    return t;
}

__device__ __forceinline__ float block_reduce_max(float val, float* red) {
    int lane = threadIdx.x & 63, wv = threadIdx.x >> 6;
#pragma unroll
    for (int off = 32; off; off >>= 1) val = fmaxf(val, __shfl_down(val, off, 64));
    if (lane == 0) red[wv] = val;
    __syncthreads();
    float t = fmaxf(fmaxf(red[0], red[1]), fmaxf(red[2], red[3]));
    __syncthreads();
    return t;
}

// ---------------- embedding: h[m][d] = tok_emb[x[m]][d] + pos_emb[m%S][d] ---
__global__ __launch_bounds__(256) void embed_kernel(
    const int* __restrict__ x, const float* __restrict__ tok,
    const float* __restrict__ pos, float* __restrict__ h) {
    int m = blockIdx.x;
    int tid = threadIdx.x;
    int s = m & (SS - 1);
    int t = x[m];
    const float4* trow = (const float4*)(tok + (size_t)t * DD);
    const float4* prow = (const float4*)(pos + (size_t)s * DD);
    float4* hrow = (float4*)(h + (size_t)m * DD);
    float4 a = trow[tid];
    float4 b = prow[tid];
    hrow[tid] = make_float4(a.x + b.x, a.y + b.y, a.z + b.z, a.w + b.w);
}

// ---------------- generic tiled fp32 GEMM ----------------------------------
// C[M,N] = A[M,K] @ B + bias[N]  (optional relu)
// BHEAD=0: B is [K,N] row-major.
// BHEAD=1: B is H blocks of [K,64] (wq[l] layout [H,D,DH]); col n maps to
//          head n/64, inner e=n%64. bias is flat [H*64] == [N].
// Tile 64x64, KT=16, 256 threads, 4x4 per thread.
template <int BHEAD, int RELU>
__global__ __launch_bounds__(256) void gemm_kernel(
    const float* __restrict__ A, const float* __restrict__ B,
    const float* __restrict__ bias, float* __restrict__ C,
    int M, int N, int K) {
    __shared__ float sA[16][68];  // transposed: sA[kk][mm]
    __shared__ float sB[16][68];  // sB[kk][nn]

    int tid = threadIdx.x;
    int tx = tid & 15;
    int ty = tid >> 4;
    int n0 = blockIdx.x * 64;
    int m0 = blockIdx.y * 64;

    const float* Bp;
    int ldb;
    if (BHEAD) {
        Bp = B + (size_t)(n0 >> 6) * K * 64;
        ldb = 64;
    } else {
        Bp = B + n0;
        ldb = N;
    }

    int amm = tid >> 2;         // 0..63
    int akk = (tid & 3) * 4;    // 0,4,8,12
    int bkk = tid >> 4;         // 0..15
    int bnn = (tid & 15) * 4;   // 0..60

    float acc[4][4] = {};

    for (int k0 = 0; k0 < K; k0 += 16) {
        float4 a4 = *(const float4*)(A + (size_t)(m0 + amm) * K + k0 + akk);
        float4 b4 = *(const float4*)(Bp + (size_t)(k0 + bkk) * ldb + bnn);
        sA[akk + 0][amm] = a4.x;
        sA[akk + 1][amm] = a4.y;
        sA[akk + 2][amm] = a4.z;
        sA[akk + 3][amm] = a4.w;
        *(float4*)&sB[bkk][bnn] = b4;
        __syncthreads();
#pragma unroll
        for (int kk = 0; kk < 16; kk++) {
            float4 av = *(const float4*)&sA[kk][ty * 4];
            float4 bv = *(const float4*)&sB[kk][tx * 4];
            acc[0][0] += av.x * bv.x; acc[0][1] += av.x * bv.y;
            acc[0][2] += av.x * bv.z; acc[0][3] += av.x * bv.w;
            acc[1][0] += av.y * bv.x; acc[1][1] += av.y * bv.y;
            acc[1][2] += av.y * bv.z; acc[1][3] += av.y * bv.w;
            acc[2][0] += av.z * bv.x; acc[2][1] += av.z * bv.y;
            acc[2][2] += av.z * bv.z; acc[2][3] += av.z * bv.w;
            acc[3][0] += av.w * bv.x; acc[3][1] += av.w * bv.y;
            acc[3][2] += av.w * bv.z; acc[3][3] += av.w * bv.w;
        }
        __syncthreads();
    }

    float4 bia = *(const float4*)(bias + n0 + tx * 4);
#pragma unroll
    for (int i = 0; i < 4; i++) {
        int mrow = m0 + ty * 4 + i;
        float4 r;
        r.x = acc[i][0] + bia.x;
        r.y = acc[i][1] + bia.y;
        r.z = acc[i][2] + bia.z;
        r.w = acc[i][3] + bia.w;
        if (RELU) {
            r.x = fmaxf(r.x, 0.f); r.y = fmaxf(r.y, 0.f);
            r.z = fmaxf(r.z, 0.f); r.w = fmaxf(r.w, 0.f);
        }
        *(float4*)(C + (size_t)mrow * N + n0 + tx * 4) = r;
    }
}

// ---------------- causal attention, one block per (b,h,s) -------------------
// q,k,v layout: [b, s, h, e] flat = [(b*S+s)*1024 + h*64 + e]
// o layout: [m][d] with d = h*64+e (ready for O-projection GEMM)
__global__ __launch_bounds__(256) void attn_kernel(
    const float* __restrict__ q, const float* __restrict__ k,
    const float* __restrict__ v, float* __restrict__ o) {
    int s = blockIdx.x, hh = blockIdx.y, b = blockIdx.z;
    int tid = threadIdx.x;
    int lane = tid & 63, wv = tid >> 6;

    __shared__ float qs[64];
    __shared__ float sc[SS];
    __shared__ float red[8];
    __shared__ float part[4][64];

    const float scale = 0.125f;  // 1/sqrt(64)
    size_t qoff = ((size_t)(b * SS + s) * HH + hh) * 64;
    if (tid < 64) qs[tid] = q[qoff + tid] * scale;
    __syncthreads();

    int nt = s + 1;
    // phase 1: scores — one key row per wave
    for (int t = wv; t < nt; t += 4) {
        const float* krow = k + ((size_t)(b * SS + t) * HH + hh) * 64;
        float val = qs[lane] * krow[lane];
#pragma unroll
        for (int off = 32; off; off >>= 1) val += __shfl_down(val, off, 64);
        if (lane == 0) sc[t] = val;
    }
    __syncthreads();

    // phase 2: softmax over sc[0..nt)
    float mx = -1e30f;
    for (int t = tid; t < nt; t += 256) mx = fmaxf(mx, sc[t]);
    mx = block_reduce_max(mx, red);
    float sum = 0.f;
    for (int t = tid; t < nt; t += 256) {
        float p = __expf(sc[t] - mx);
        sc[t] = p;
        sum += p;
    }
    sum = block_reduce_sum(sum, red);
    float inv = 1.0f / sum;

    // phase 3: o[e] = inv * sum_t p[t] * v[t][e]
    int e = tid & 63, c = tid >> 6;
    float acc = 0.f;
    for (int t = c; t < nt; t += 4)
        acc += sc[t] * v[((size_t)(b * SS + t) * HH + hh) * 64 + e];
    part[c][e] = acc;
    __syncthreads();
    if (tid < 64) {
        float r = (part[0][tid] + part[1][tid] + part[2][tid] + part[3][tid]) * inv;
        o[(size_t)(b * SS + s) * DD + hh * 64 + tid] = r;
    }
}

// ---------------- LayerNorm(residual): h = LN(tmp + h) * g + b --------------
__global__ __launch_bounds__(256) void ln_res_kernel(
    const float* __restrict__ tmp, float* __restrict__ hbuf,
    const float* __restrict__ g, const float* __restrict__ bta) {
    __shared__ float red[8];
    int m = blockIdx.x, tid = threadIdx.x;
    const float* trow = tmp + (size_t)m * DD;
    float* hrow = hbuf + (size_t)m * DD;
    float v0[4];
    float sum = 0.f;
#pragma unroll
    for (int i = 0; i < 4; i++) {
        int d = tid + 256 * i;
        v0[i] = trow[d] + hrow[d];
        sum += v0[i];
    }
    sum = block_reduce_sum(sum, red);
    float mu = sum * (1.0f / DD);
    float var = 0.f;
#pragma unroll
    for (int i = 0; i < 4; i++) {
        float xv = v0[i] - mu;
        var += xv * xv;
    }
    var = block_reduce_sum(var, red);
    float rstd = rsqrtf(var * (1.0f / DD) + 1e-5f);
#pragma unroll
    for (int i = 0; i < 4; i++) {
        int d = tid + 256 * i;
        hrow[d] = (v0[i] - mu) * rstd * g[d] + bta[d];
    }
}

// ---------------- in-place log_softmax over V=32000 per row -----------------
__global__ __launch_bounds__(256) void logsoftmax_kernel(float* __restrict__ out) {
    __shared__ float red[8];
    int m = blockIdx.x, tid = threadIdx.x;
    float* row = out + (size_t)m * VV;
    float mx = -1e30f;
    for (int t = tid; t < VV; t += 256) mx = fmaxf(mx, row[t]);
    mx = block_reduce_max(mx, red);
    float sum = 0.f;
    for (int t = tid; t < VV; t += 256) sum += __expf(row[t] - mx);
    sum = block_reduce_sum(sum, red);
    float lse = mx + logf(sum);
    for (int t = tid; t < VV; t += 256) row[t] = row[t] - lse;
}

// ---------------- launch ----------------------------------------------------
extern "C" void kernel_launch(void* const* d_in, const int* in_sizes, int n_in,
                              void* d_out, int out_size, void* d_ws, size_t ws_size,
                              hipStream_t stream) {
    const int* x = (const int*)d_in[0];
    const float* tok = (const float*)d_in[1];
    const float* pos = (const float*)d_in[2];
    const float* wq = (const float*)d_in[3];
    const float* bq = (const float*)d_in[4];
    const float* wk = (const float*)d_in[5];
    const float* bk = (const float*)d_in[6];
    const float* wv = (const float*)d_in[7];
    const float* bv = (const float*)d_in[8];
    const float* wo = (const float*)d_in[9];
    const float* bo = (const float*)d_in[10];
    const float* ln1g = (const float*)d_in[11];
    const float* ln1b = (const float*)d_in[12];
    const float* w1 = (const float*)d_in[13];
    const float* b1 = (const float*)d_in[14];
    const float* w2 = (const float*)d_in[15];
    const float* b2 = (const float*)d_in[16];
    const float* ln2g = (const float*)d_in[17];
    const float* ln2b = (const float*)d_in[18];
    const float* wout = (const float*)d_in[19];
    const float* bout = (const float*)d_in[20];
    float* out = (float*)d_out;
    float* ws = (float*)d_ws;

    // workspace layout (floats):
    // h: 2M | big: 8M (q,k,v share first 6M; ff uses all 8M) | o: 2M | t1: 2M
    const size_t SZ = (size_t)MM * DD;  // 2M floats
    float* h = ws;
    float* big = ws + SZ;
    float* qb = big;
    float* kb = big + SZ;
    float* vb = big + 2 * SZ;
    float* ffb = big;  // reuses q/k/v space (8M floats)
    float* ob = ws + 5 * SZ;
    float* t1 = ws + 6 * SZ;

    const size_t wqk_l = (size_t)HH * DD * DHH;  // 1,048,576
    const size_t wo_l = (size_t)DD * DD;
    const size_t w1_l = (size_t)DD * FFDIM;
    const size_t w2_l = (size_t)FFDIM * DD;

    dim3 blk(256);

    embed_kernel<<<MM, blk, 0, stream>>>(x, tok, pos, h);

    for (int l = 0; l < LL; l++) {
        // QKV projections (head-batched weight layout [H,D,DH])
        gemm_kernel<1, 0><<<dim3(DD / 64, MM / 64), blk, 0, stream>>>(
            h, wq + l * wqk_l, bq + (size_t)l * DD, qb, MM, DD, DD);
        gemm_kernel<1, 0><<<dim3(DD / 64, MM / 64), blk, 0, stream>>>(
            h, wk + l * wqk_l, bk + (size_t)l * DD, kb, MM, DD, DD);
        gemm_kernel<1, 0><<<dim3(DD / 64, MM / 64), blk, 0, stream>>>(
            h, wv + l * wqk_l, bv + (size_t)l * DD, vb, MM, DD, DD);

        attn_kernel<<<dim3(SS, HH, BB), blk, 0, stream>>>(qb, kb, vb, ob);

        // O-projection
        gemm_kernel<0, 0><<<dim3(DD / 64, MM / 64), blk, 0, stream>>>(
            ob, wo + l * wo_l, bo + (size_t)l * DD, t1, MM, DD, DD);
        ln_res_kernel<<<MM, blk, 0, stream>>>(t1, h, ln1g + (size_t)l * DD,
                                              ln1b + (size_t)l * DD);

        // FF
        gemm_kernel<0, 1><<<dim3(FFDIM / 64, MM / 64), blk, 0, stream>>>(
            h, w1 + l * w1_l, b1 + (size_t)l * FFDIM, ffb, MM, FFDIM, DD);
        gemm_kernel<0, 0><<<dim3(DD / 64, MM / 64), blk, 0, stream>>>(
            ffb, w2 + l * w2_l, b2 + (size_t)l * DD, t1, MM, DD, FFDIM);
        ln_res_kernel<<<MM, blk, 0, stream>>>(t1, h, ln2g + (size_t)l * DD,
                                              ln2b + (size_t)l * DD);
    }

    // logits straight into d_out, then in-place log_softmax
    gemm_kernel<0, 0><<<dim3(VV / 64, MM / 64), blk, 0, stream>>>(
        h, wout, bout, out, MM, VV, DD);
    logsoftmax_kernel<<<MM, blk, 0, stream>>>(out);
}